// Round 6
// baseline (197.560 us; speedup 1.0000x reference)
//
#include <hip/hip_runtime.h>

// STDP delta_w on MI355X, bf16-MFMA formulation (2-dispatch).
//   term1: dW1[o,p] = sum_k O[k,o]*TP[k,p], K = T*B = 1024  -> bf16 MFMA GEMM
//   term2: -coef[o]*W[o,p], coef[o] = sum_k O[k,o]*PO[k,o]  -> fp32 epilogue
//
// R12: LDS-FREE GEMM. Four schedule variants (R6/R8/R9/R11) tied at 67-69 us,
//   MfmaUtil ~19%, nothing saturated -> the shared glds->barrier->ds_read
//   operand path is the limiter. Fix: workspace stored FRAGMENT-MAJOR:
//     FA[mt 256][kb 32][lane 64][8] bf16  (16 B per lane = one A-fragment)
//   GEMM loads operands global->reg (coalesced 1 KB/instr, L1/L2-served,
//   16 MB total), zero LDS, zero barriers; latency hidden by TLP + 1-deep
//   named-set register double buffer. Converter: recurrence/coef identical
//   to R10 (passed); only the flush gather/store indexing changed to emit
//   fragment-major layout.
//
// ws: FA bf16 [256][32][64][8] (8MB) | FB same (8MB) | coef f32[4096]

#define T_STEPS 64
#define B_SZ    16
#define PRE     4096
#define POST    4096
#define K_TOT   1024

typedef __attribute__((ext_vector_type(8))) unsigned short ushort8;
typedef __attribute__((ext_vector_type(8))) __bf16 bf16x8;
typedef __attribute__((ext_vector_type(4))) float floatx4;

__device__ __forceinline__ unsigned short f2bf(float f) {
    unsigned int u = __float_as_uint(f);
    u += 0x7fff + ((u >> 16) & 1);          // round-to-nearest-even
    return (unsigned short)(u >> 16);
}

// ---------------------------------------------------------------------------
// Converter R12: grid = 512 blocks (matrix = blk>>8, p-chunk16 = blk&255),
// 256 thr; thread owns chain (b = tid>>4, p = tid&15) for all 64 t.
// Recurrence + coef identical to R10 (passed). Flush writes fragment-major:
//   FA[(MT*32 + kb)*512 + l*8 + s] = bf16( row p0+(l&15),
//                                          k = kb*32 + (l>>4)*8 + s )
// where MT = p0>>4, k = t*16 + b (same k-ordering as all passing rounds).
__global__ __launch_bounds__(256) void trace_convert(
        const float* __restrict__ in_spikes,
        const float* __restrict__ out_spikes,
        unsigned short* __restrict__ FA,
        unsigned short* __restrict__ FB,
        float* __restrict__ coef) {
    __shared__ unsigned short ot[128 * 17];  // [128 k_local][16 p + 1 pad]
    __shared__ float cbuf[16 * 17];
    const int tid  = threadIdx.x;
    const bool isA = blockIdx.x >= 256;
    const int p0 = (blockIdx.x & 255) * 16;
    const float* src = isA ? out_spikes : in_spikes;
    unsigned short* dst = isA ? FA : FB;

    const int p = tid & 15;
    const int b = tid >> 4;
    const float* gbase = src + (size_t)b * PRE + p0 + p;

    // flush mapping: kbl = tid>>6 (kb within chunk), l = tid&63
    const int kbl = tid >> 6;
    const int l   = tid & 63;
    const int lq  = l >> 4;                  // k-quad of the fragment
    const int lr  = l & 15;                  // row within tile
    unsigned short* dstf = dst + (size_t)(p0 >> 4) * 16384 + kbl * 512 + l * 8;

    float x[2][8];
    float st = 0.f, c0 = 0.f;

    #pragma unroll
    for (int tl = 0; tl < 8; ++tl) x[0][tl] = gbase[(size_t)tl * 65536];

    #pragma unroll
    for (int c = 0; c < 8; ++c) {
        if (c < 7) {
            #pragma unroll
            for (int tl = 0; tl < 8; ++tl)
                x[(c + 1) & 1][tl] = gbase[(size_t)((c + 1) * 8 + tl) * 65536];
        }
        #pragma unroll
        for (int tl = 0; tl < 8; ++tl) {
            const float xv = x[c & 1][tl];
            unsigned short ov;
            if (isA) {
                st = 0.5f * st + xv;         // po update
                c0 += xv * st;               // o * po
                ov = f2bf(xv);               // A stores raw o
            } else {
                st = fminf(fmaxf(0.5f * st + xv, 0.f), 1.f);
                ov = f2bf(st);               // B stores clipped trace
            }
            ot[(tl * 16 + b) * 17 + p] = ov;
        }
        asm volatile("s_waitcnt lgkmcnt(0)" ::: "memory");
        __builtin_amdgcn_s_barrier();
        __builtin_amdgcn_sched_barrier(0);

        // flush chunk c: kb_global = c*4 + kbl; gather 8 u16 from ot
        ushort8 v;
        #pragma unroll
        for (int s = 0; s < 8; ++s)
            v[s] = ot[(kbl * 32 + lq * 8 + s) * 17 + lr];
        *(ushort8*)&dstf[(size_t)c * 2048] = v;

        asm volatile("s_waitcnt lgkmcnt(0)" ::: "memory");
        __builtin_amdgcn_s_barrier();
        __builtin_amdgcn_sched_barrier(0);
    }

    if (isA) {
        cbuf[b * 17 + p] = c0;
        asm volatile("s_waitcnt lgkmcnt(0)" ::: "memory");
        __builtin_amdgcn_s_barrier();
        if (tid < 16) {
            float s = 0.f;
            #pragma unroll
            for (int r = 0; r < 16; ++r) s += cbuf[r * 17 + tid];
            coef[p0 + tid] = s;
        }
    }
}

// ---------------------------------------------------------------------------
// R12 GEMM: LDS-free, barrier-free. 128x128 block tile, 4 waves (2m x 2n),
// per wave 4x4 16x16 tiles. Operands loaded fragment-major global->reg
// (bf16x8 = 16 B/lane, coalesced). 1-deep register double buffer with NAMED
// sets (rule #20). Epilogue: C = acc - coef[o]*W, nontemporal (R11-verified).
__global__ __launch_bounds__(256) void stdp_gemm_mfma(
        const unsigned short* __restrict__ FA,   // [256 mt][32 kb][64 l][8]
        const unsigned short* __restrict__ FB,   // [256 nt][32 kb][64 l][8]
        const float* __restrict__ W,             // [POST][PRE]
        const float* __restrict__ coef,          // [POST]
        float* __restrict__ Cout) {              // [POST][PRE]
    const int tid  = threadIdx.x;
    const int lane = tid & 63;
    const int wave = tid >> 6;

    // XCD-bijective swizzle: 1024 blocks = 8 XCD x 128 (m-major within XCD).
    const int bid = blockIdx.x;
    const int f   = (bid & 7) * 128 + (bid >> 3);
    const int mt0 = (f >> 5) * 8;                // m-tile base (of 16 rows)
    const int nt0 = (f & 31) * 8;                // n-tile base

    const int wmt = (wave >> 1) * 4;             // wave m-tile offset
    const int wnt = (wave & 1) * 4;              // wave n-tile offset

    floatx4 acc[4][4];
    #pragma unroll
    for (int i = 0; i < 4; ++i)
        #pragma unroll
        for (int j = 0; j < 4; ++j)
            acc[i][j] = (floatx4){0.f, 0.f, 0.f, 0.f};

    // Per-tile fragment streams: frag(MT, kb) at FA + MT*16384 + kb*512 + lane*8
    const unsigned short* pa[4];
    const unsigned short* pb[4];
    #pragma unroll
    for (int i = 0; i < 4; ++i) {
        pa[i] = FA + (size_t)(mt0 + wmt + i) * 16384 + lane * 8;
        pb[i] = FB + (size_t)(nt0 + wnt + i) * 16384 + lane * 8;
    }

    #define LOADSET(AA, BB, kb)                                                \
        do {                                                                   \
            _Pragma("unroll")                                                  \
            for (int i_ = 0; i_ < 4; ++i_) {                                   \
                AA[i_] = *(const bf16x8*)(pa[i_] + (size_t)(kb) * 512);        \
                BB[i_] = *(const bf16x8*)(pb[i_] + (size_t)(kb) * 512);        \
            }                                                                  \
        } while (0)

    #define MFMASET(AA, BB)                                                    \
        do {                                                                   \
            _Pragma("unroll")                                                  \
            for (int mi = 0; mi < 4; ++mi)                                     \
                _Pragma("unroll")                                              \
                for (int ni = 0; ni < 4; ++ni)                                 \
                    acc[mi][ni] = __builtin_amdgcn_mfma_f32_16x16x32_bf16(     \
                        AA[mi], BB[ni], acc[mi][ni], 0, 0, 0);                 \
        } while (0)

    bf16x8 a0[4], b0[4], a1[4], b1[4];           // named double-buffer sets
    LOADSET(a0, b0, 0);
    #pragma unroll 4
    for (int kb2 = 0; kb2 < 16; ++kb2) {
        const int k1 = 2 * kb2 + 1;
        const int k2 = (2 * kb2 + 2) & 31;       // wraps to 0 at end (unused)
        LOADSET(a1, b1, k1);
        MFMASET(a0, b0);
        LOADSET(a0, b0, k2);
        MFMASET(a1, b1);
    }
    #undef LOADSET
    #undef MFMASET

    // Epilogue: C = acc - coef[o]*W. C/D layout: col=lane&15, row=quad*4+reg.
    const int colp = (nt0 + wnt) * 16 + (lane & 15);
    const int rowb = (mt0 + wmt) * 16 + (lane >> 4) * 4;
    #pragma unroll
    for (int mi = 0; mi < 4; ++mi) {
        #pragma unroll
        for (int r = 0; r < 4; ++r) {
            const int o = rowb + mi * 16 + r;
            const float cf = coef[o];
            const float* wr = &W[(size_t)o * PRE];
            float* cr = &Cout[(size_t)o * PRE];
            #pragma unroll
            for (int ni = 0; ni < 4; ++ni) {
                const int p = colp + ni * 16;
                const float wv = __builtin_nontemporal_load(&wr[p]);
                __builtin_nontemporal_store(acc[mi][ni][r] - cf * wv, &cr[p]);
            }
        }
    }
}

// ---------------------------------------------------------------------------
extern "C" void kernel_launch(void* const* d_in, const int* in_sizes, int n_in,
                              void* d_out, int out_size, void* d_ws, size_t ws_size,
                              hipStream_t stream) {
    const float* in_spikes  = (const float*)d_in[0];
    const float* out_spikes = (const float*)d_in[1];
    const float* weight     = (const float*)d_in[2];
    float* out = (float*)d_out;

    unsigned short* FA = (unsigned short*)d_ws;                 // 8 MB
    unsigned short* FB = FA + (size_t)POST * K_TOT;             // 8 MB
    float* coef = (float*)(FB + (size_t)PRE * K_TOT);           // 16 KB

    trace_convert<<<512, 256, 0, stream>>>(in_spikes, out_spikes, FA, FB, coef);

    stdp_gemm_mfma<<<1024, 256, 0, stream>>>(FA, FB, weight, coef, out);
}

// Round 7
// 180.653 us; speedup vs baseline: 1.0936x; 1.0936x over previous
//
#include <hip/hip_runtime.h>

// STDP delta_w on MI355X, bf16-MFMA formulation (2-dispatch).
//   term1: dW1[o,p] = sum_k O[k,o]*TP[k,p], K = T*B = 1024  -> bf16 MFMA GEMM
//   term2: -coef[o]*W[o,p], coef[o] = sum_k O[k,o]*PO[k,o]  -> fp32 epilogue
//
// R13: RESTORE measured-best build (Round 3: R4 converter + R9 8-phase GEMM,
//   180.8 us total, GEMM 67.4 avg, FETCH 69.7 MB). Post-mortem of R6-R12:
//   five structurally different GEMM schedules (drain / coarse-vmcnt /
//   8-phase / 2-block-dbuf / LDS-free) land at 67-78 us with MfmaUtil,
//   VALUBusy, Occupancy pinned at 17-20% / 8-12% / 17-19% regardless of
//   LDS (0-144 KB) or VGPR (88-128) budget -> plateau is schedule- and
//   resource-invariant at HIP-source level under this harness.
//
// ws: AT bf16 [4096][1024] (8MB) | BT bf16 [4096][1024] (8MB) | coef f32[4096]

#define T_STEPS 64
#define B_SZ    16
#define PRE     4096
#define POST    4096
#define K_TOT   1024

typedef __attribute__((ext_vector_type(8))) unsigned short ushort8;
typedef __attribute__((ext_vector_type(8))) __bf16 bf16x8;
typedef __attribute__((ext_vector_type(4))) float floatx4;

__device__ __forceinline__ unsigned short f2bf(float f) {
    unsigned int u = __float_as_uint(f);
    u += 0x7fff + ((u >> 16) & 1);          // round-to-nearest-even
    return (unsigned short)(u >> 16);
}

__device__ __forceinline__ void glds16(const void* g, void* l) {
    __builtin_amdgcn_global_load_lds((const __attribute__((address_space(1))) void*)g,
                                     (__attribute__((address_space(3))) void*)l,
                                     16, 0, 0);
}

// ---------------------------------------------------------------------------
// Converter: grid = 256 blocks (matrix = blk>>7, p-chunk = blk&127), 256 thr.
// (verbatim R4 — passed repeatedly)
__global__ __launch_bounds__(256) void trace_convert(
        const float* __restrict__ in_spikes,
        const float* __restrict__ out_spikes,
        unsigned short* __restrict__ AT,
        unsigned short* __restrict__ BT,
        float* __restrict__ coef) {
    __shared__ float ldsf[4096];             // [8 t][16 b][32 p] fp32, 16 KB
    __shared__ unsigned short ot[128 * 34];  // [128 k][32 p + 2 pad], 8.5 KB
    __shared__ float cbuf[8][33];
    const int tid  = threadIdx.x;
    const int wave = tid >> 6;
    const int lane = tid & 63;
    const bool isA = blockIdx.x >= 128;
    const int p0 = (blockIdx.x & 127) * 32;
    const float* src = isA ? out_spikes : in_spikes;
    unsigned short* dst = isA ? AT : BT;

    const int bA = tid >> 5;                 // chains (bA, p) and (bA+8, p)
    const int pA = tid & 31;

    float st0 = 0.f, st1 = 0.f, c0 = 0.f, c1 = 0.f;

    for (int tc = 0; tc < 8; ++tc) {
        const int T0 = tc * 8;
        // ---- stage 16 b x 8 t x 32 p fp32 into LDS (4 glds x16B per wave)
        #pragma unroll
        for (int i = 0; i < 4; ++i) {
            const int q  = (wave * 4 + i) * 64 + lane;  // float-quad id 0..1023
            const int p  = (q & 7) * 4;
            const int b  = (q >> 3) & 15;
            const int tl = q >> 7;
            const float* g = src + ((size_t)((T0 + tl) * 16 + b)) * 4096 + p0 + p;
            glds16(g, (char*)ldsf + (size_t)(wave * 4 + i) * 1024);
        }
        __syncthreads();                     // drains vmcnt

        // ---- recurrence: 8 t-steps, 2 chains per thread
        #pragma unroll
        for (int tl = 0; tl < 8; ++tl) {
            const float x0 = ldsf[tl * 512 + bA * 32 + pA];
            const float x1 = ldsf[tl * 512 + (bA + 8) * 32 + pA];
            if (isA) {
                st0 = 0.5f * st0 + x0; c0 += x0 * st0;   // po update, then o*po
                st1 = 0.5f * st1 + x1; c1 += x1 * st1;
                ot[(tl * 16 + bA)     * 34 + pA] = f2bf(x0);
                ot[(tl * 16 + bA + 8) * 34 + pA] = f2bf(x1);
            } else {
                st0 = fminf(fmaxf(0.5f * st0 + x0, 0.f), 1.f);
                st1 = fminf(fmaxf(0.5f * st1 + x1, 0.f), 1.f);
                ot[(tl * 16 + bA)     * 34 + pA] = f2bf(st0);
                ot[(tl * 16 + bA + 8) * 34 + pA] = f2bf(st1);
            }
        }
        __syncthreads();

        // ---- flush: 128 contiguous k per p-row, 16-B vector stores
        const int pf = tid >> 3;             // 0..31
        const int c8 = tid & 7;
        #pragma unroll
        for (int i = 0; i < 2; ++i) {
            const int ch = c8 + i * 8;       // 16-B chunk 0..15
            ushort8 v;
            #pragma unroll
            for (int s = 0; s < 8; ++s) v[s] = ot[(ch * 8 + s) * 34 + pf];
            *(ushort8*)&dst[(size_t)(p0 + pf) * K_TOT + T0 * 16 + ch * 8] = v;
        }
    }

    if (isA) {
        cbuf[bA][pA] = c0 + c1;              // partial over b in {bA, bA+8}
        __syncthreads();
        if (tid < 32) {
            float s = 0.f;
            #pragma unroll
            for (int r = 0; r < 8; ++r) s += cbuf[r][tid];
            coef[p0 + tid] = s;
        }
    }
}

// ---------------------------------------------------------------------------
// 8-phase GEMM — verbatim R9 (best measured: 67.4 us avg, FETCH 69.7 MB).
#define NTILES 16
#define LOFF(buf, isB, kh) ((buf) * 65536 + (isB) * 32768 + (kh) * 16384)

__global__ __launch_bounds__(512, 2) void stdp_gemm_mfma(
        const unsigned short* __restrict__ AT,   // [POST][K] bf16 bits
        const unsigned short* __restrict__ BT,   // [PRE][K]  bf16 bits
        const float* __restrict__ W,             // [POST][PRE]
        const float* __restrict__ coef,          // [POST]
        float* __restrict__ Cout) {              // [POST][PRE]
    __shared__ __align__(16) char ldsraw[131072];   // 128 KB -> 1 block/CU

    const int tid  = threadIdx.x;
    const int lane = tid & 63;
    const int wave = tid >> 6;

    // XCD-bijective swizzle: 256 blocks = 8 XCD x 32; each XCD: 2 m-panels x 16 n.
    const int bid = blockIdx.x;
    const int f   = (bid & 7) * 32 + (bid >> 3);
    const int m0  = (f >> 4) * 256;
    const int n0  = (f & 15) * 256;

    const int wm  = (wave >> 2) * 128;           // 2 M-groups (rows within tile)
    const int wn  = (wave & 3) * 64;             // 4 N-groups
    const int rml = lane & 15;                   // fragment row within 16
    const int q   = lane >> 4;                   // k-chunk 0..3 within 32-k half
    const int swz16 = ((q ^ ((rml >> 1) & 3)) << 4);  // swizzled chunk byte offset

    floatx4 acc[8][4];
    #pragma unroll
    for (int i = 0; i < 8; ++i)
        #pragma unroll
        for (int j = 0; j < 4; ++j)
            acc[i][j] = (floatx4){0.f, 0.f, 0.f, 0.f};
    bf16x8 bv[4];                                // B-frags, live across phase pairs

    const int cid0 = wave * 64 + lane;
    const int row0 = cid0 >> 2;
    const int g0   = (cid0 & 3) ^ ((row0 >> 1) & 3);
    const unsigned short* gA0 = AT + (size_t)(m0 + row0) * K_TOT + g0 * 8;
    const unsigned short* gB0 = BT + (size_t)(n0 + row0) * K_TOT + g0 * 8;

    #define STG(isB, t, kh)                                                        \
        do {                                                                       \
            const unsigned short* s0_ = ((isB) ? gB0 : gA0) + (t) * 64 + (kh) * 32;\
            char* d_ = ldsraw + LOFF((t) & 1, (isB), (kh)) + wave * 1024;          \
            glds16(s0_, d_);                                                       \
            glds16(s0_ + (size_t)128 * K_TOT, d_ + 8192);                          \
        } while (0)

    #define PHASE(bufc, khc, mqc, SISB, ST, SKH, SCOND, WM)                        \
        do {                                                                       \
            const char* Ab_ = ldsraw + LOFF(bufc, 0, khc);                         \
            const char* Bb_ = ldsraw + LOFF(bufc, 1, khc);                         \
            if ((mqc) == 0) {                                                      \
                _Pragma("unroll")                                                  \
                for (int ni = 0; ni < 4; ++ni)                                     \
                    bv[ni] = *(const bf16x8*)(Bb_ + (wn + ni * 16 + rml) * 64 + swz16); \
            }                                                                      \
            bf16x8 af_[4];                                                         \
            _Pragma("unroll")                                                      \
            for (int k4 = 0; k4 < 4; ++k4)                                         \
                af_[k4] = *(const bf16x8*)(Ab_ + (wm + (mqc) * 64 + k4 * 16 + rml) * 64 + swz16); \
            if (SCOND) STG(SISB, ST, SKH);                                         \
            if ((WM) == 1)      asm volatile("s_waitcnt vmcnt(4)" ::: "memory");   \
            else if ((WM) == 2) asm volatile("s_waitcnt vmcnt(0)" ::: "memory");   \
            __builtin_amdgcn_s_barrier();                                          \
            __builtin_amdgcn_sched_barrier(0);                                     \
            __builtin_amdgcn_s_setprio(1);                                         \
            _Pragma("unroll")                                                      \
            for (int k4 = 0; k4 < 4; ++k4)                                         \
                _Pragma("unroll")                                                  \
                for (int ni = 0; ni < 4; ++ni)                                     \
                    acc[(mqc) * 4 + k4][ni] = __builtin_amdgcn_mfma_f32_16x16x32_bf16( \
                        af_[k4], bv[ni], acc[(mqc) * 4 + k4][ni], 0, 0, 0);        \
            __builtin_amdgcn_s_setprio(0);                                         \
            __builtin_amdgcn_s_barrier();                                          \
            __builtin_amdgcn_sched_barrier(0);                                     \
        } while (0)

    STG(0, 0, 0); STG(1, 0, 0); STG(0, 0, 1); STG(1, 0, 1);
    STG(0, 1, 0); STG(1, 1, 0); STG(0, 1, 1); STG(1, 1, 1);
    asm volatile("s_waitcnt vmcnt(8)" ::: "memory");
    __builtin_amdgcn_s_barrier();
    __builtin_amdgcn_sched_barrier(0);

    for (int i = 0; i < 8; ++i) {
        const int t2 = 2 * i + 2, t3 = 2 * i + 3, tA = 2 * i + 1;
        const int wm4 = (i < 7) ? 1 : 2;         // ph4 wait: publish buf1
        const int wm8 = (i < 7) ? 1 : 0;         // ph8 wait: publish buf0 (none at end)
        PHASE(0, 0, 0, 0, tA, 1, i > 0,      0);     // ph1
        PHASE(0, 0, 1, 1, tA, 1, i > 0,      0);     // ph2
        PHASE(0, 1, 0, 0, t2, 0, t2 < NTILES, 0);    // ph3
        PHASE(0, 1, 1, 1, t2, 0, t2 < NTILES, wm4);  // ph4
        PHASE(1, 0, 0, 0, t2, 1, t2 < NTILES, 0);    // ph5
        PHASE(1, 0, 1, 1, t2, 1, t2 < NTILES, 0);    // ph6
        PHASE(1, 1, 0, 0, t3, 0, t3 < NTILES, 0);    // ph7
        PHASE(1, 1, 1, 1, t3, 0, t3 < NTILES, wm8);  // ph8
    }

    // Epilogue: C = acc - coef[o]*W. C/D layout: col=lane&15, row=quad*4+reg.
    const int colp = n0 + wn + rml;
    const int q4   = lane >> 4;
    #pragma unroll
    for (int mi = 0; mi < 8; ++mi) {
        #pragma unroll
        for (int r = 0; r < 4; ++r) {
            const int o = m0 + wm + mi * 16 + q4 * 4 + r;
            const float cf = coef[o];
            const float* wrow = &W[(size_t)o * PRE + colp];
            float* crow = &Cout[(size_t)o * PRE + colp];
            #pragma unroll
            for (int ni = 0; ni < 4; ++ni)
                crow[ni * 16] = acc[mi][ni][r] - cf * wrow[ni * 16];
        }
    }
    #undef PHASE
    #undef STG
}

// ---------------------------------------------------------------------------
extern "C" void kernel_launch(void* const* d_in, const int* in_sizes, int n_in,
                              void* d_out, int out_size, void* d_ws, size_t ws_size,
                              hipStream_t stream) {
    const float* in_spikes  = (const float*)d_in[0];
    const float* out_spikes = (const float*)d_in[1];
    const float* weight     = (const float*)d_in[2];
    float* out = (float*)d_out;

    unsigned short* AT = (unsigned short*)d_ws;                 // 8 MB
    unsigned short* BT = AT + (size_t)POST * K_TOT;             // 8 MB
    float* coef = (float*)(BT + (size_t)PRE * K_TOT);           // 16 KB

    trace_convert<<<256, 256, 0, stream>>>(in_spikes, out_spikes, AT, BT, coef);

    stdp_gemm_mfma<<<256, 512, 0, stream>>>(AT, BT, weight, coef, out);
}